// Round 6
// baseline (234.271 us; speedup 1.0000x reference)
//
#include <hip/hip_runtime.h>

#define B_ 16
#define N_ 512
#define D_ 64
#define K_ 8

// ---------------- ws layout ----------------
// wsu : [B][N][N] uint {kin*128 | (kout*128)<<16}   16,777,216 B
// Tin : [B][N][9][64] bf16                           9,437,184 B
// Tout: [B][N][9][64] bf16                           9,437,184 B
// hbf : [B][N][64] bf16                              1,048,576 B
// Mbf : [2][8][64][64] bf16                            131,072 B
#define WSU_BYTES ((size_t)B_ * N_ * N_ * 4)
#define T_BYTES   ((size_t)B_ * N_ * (K_ + 1) * D_ * 2)
#define HBF_BYTES ((size_t)B_ * N_ * D_ * 2)
#define MBF_BYTES ((size_t)2 * K_ * D_ * D_ * 2)
#define TROWB 1152  // (K+1)*D*2 bytes per j row

typedef __attribute__((ext_vector_type(8))) short bf8_t;   // 8 bf16
typedef __attribute__((ext_vector_type(4))) float f4_t;    // 4 f32 acc

__device__ __forceinline__ unsigned short f2bf(float x) {  // RNE f32->bf16
  union { float f; unsigned u; } c; c.f = x;
  unsigned r = c.u + 0x7FFFu + ((c.u >> 16) & 1u);
  return (unsigned short)(r >> 16);
}

// ---------- kernel 0: bf16 conversions + zero T slot 0 + zero out ----------
__global__ __launch_bounds__(256) void conv_inputs(
    const float* __restrict__ h, const float* __restrict__ Min,
    const float* __restrict__ Mout,
    unsigned short* __restrict__ hbf, unsigned short* __restrict__ Mbf,
    unsigned short* __restrict__ Tin, unsigned short* __restrict__ Tout,
    float* __restrict__ out) {
  const int g = blockIdx.x * 256 + threadIdx.x;   // 131072 threads
  {  // h: 131072 float4 groups
    const float4 v = ((const float4*)h)[g];
    ushort4 o; o.x = f2bf(v.x); o.y = f2bf(v.y); o.z = f2bf(v.z); o.w = f2bf(v.w);
    ((ushort4*)hbf)[g] = o;
  }
  if (g < 8192) {          // Min
    const float4 v = ((const float4*)Min)[g];
    ushort4 o; o.x = f2bf(v.x); o.y = f2bf(v.y); o.z = f2bf(v.z); o.w = f2bf(v.w);
    ((ushort4*)Mbf)[g] = o;
  } else if (g < 16384) {  // Mout
    const int t = g - 8192;
    const float4 v = ((const float4*)Mout)[t];
    ushort4 o; o.x = f2bf(v.x); o.y = f2bf(v.y); o.z = f2bf(v.z); o.w = f2bf(v.w);
    ((ushort4*)Mbf)[8192 + t] = o;
  }
  {  // zero slot k=0 of T: 8192 rows x 16 ushort4 chunks
    const int row = g >> 4, part = g & 15;
    const ushort4 z = make_ushort4(0, 0, 0, 0);
    ((ushort4*)(Tin  + (size_t)row * 576))[part] = z;
    ((ushort4*)(Tout + (size_t)row * 576))[part] = z;
  }
  {  // zero out[]: 262144 float4 -> 2 per thread (gather atomically accumulates)
    const float4 z4 = make_float4(0.f, 0.f, 0.f, 0.f);
    ((float4*)out)[g]          = z4;
    ((float4*)out)[g + 131072] = z4;
  }
}

// ---------- kernel A: transpose + pack PRE-SHIFTED edge offsets ----------
__global__ __launch_bounds__(256) void prep_adj(const int* __restrict__ adj,
                                                unsigned* __restrict__ wsu) {
  __shared__ int ta[64][65];
  __shared__ int tb[64][65];
  const int blk = blockIdx.x;          // 1024
  const int xcd = blk & 7, rest = blk >> 3;
  const int b = xcd + 8 * (rest & 1);  // batch b -> XCD b%8
  const int tile = rest >> 1;          // 0..63
  const int i0 = (tile >> 3) * 64, j0 = (tile & 7) * 64;
  const int lane = threadIdx.x & 63, w = threadIdx.x >> 6;
  const int* ab = adj + (size_t)b * N_ * N_;
#pragma unroll
  for (int r = w; r < 64; r += 4) {
    ta[r][lane] = ab[(size_t)(i0 + r) * N_ + j0 + lane];
    tb[r][lane] = ab[(size_t)(j0 + r) * N_ + i0 + lane];
  }
  __syncthreads();
  unsigned* wb = wsu + (size_t)b * N_ * N_;
#pragma unroll
  for (int r = w; r < 64; r += 4) {
    wb[(size_t)(i0 + r) * N_ + j0 + lane] =
        (unsigned)(ta[r][lane] << 7) | ((unsigned)tb[lane][r] << 23);
  }
}

// ---------- kernel B: T = M' x h^T via MFMA, packed dwordx2 stores ----------
// D[m=kd, n=j]: A-frag = Mbf rows (kd), B-frag = hbf rows (j); lane holds
// 4 consecutive kd at one j -> one 8B store per fragment. (m89 layout)
__global__ __launch_bounds__(256) void build_T_mfma(
    const unsigned short* __restrict__ hbf,   // [B][N][64]
    const unsigned short* __restrict__ Mbf,   // [1024][64]
    unsigned short* __restrict__ Tin,
    unsigned short* __restrict__ Tout) {
  const int blk = blockIdx.x;               // 2048
  const int b   = (blk & 7) + 8 * ((blk >> 3) & 1);
  const int u   = blk >> 4;                 // 0..127
  const int kdt = u >> 3;                   // 0..15 : kd-tile of 64
  const int jt4 = u & 7;                    // 0..7  : 4 j-tiles of 16 per block
  const int w = threadIdx.x >> 6, l = threadIdx.x & 63;
  const int j0  = (jt4 * 4 + w) * 16;
  const int kd0 = kdt * 64;
  const int r16 = l & 15, grp = l >> 4;

  // B-operand: h row (j = j0 + r16), 16B per k-step
  const unsigned short* hr = hbf + ((size_t)(b * N_ + j0 + r16)) * 64 + grp * 8;
  bf8_t hfr[2];
  hfr[0] = *(const bf8_t*)(hr);
  hfr[1] = *(const bf8_t*)(hr + 32);

  // A-operand: M' rows (kd = kd0 + fc*16 + r16)
  const unsigned short* mr = Mbf + (size_t)(kd0 + r16) * 64 + grp * 8;

  f4_t acc[4];
#pragma unroll
  for (int fc = 0; fc < 4; ++fc) acc[fc] = (f4_t)(0.f);
#pragma unroll
  for (int fc = 0; fc < 4; ++fc) {
    const bf8_t a0 = *(const bf8_t*)(mr + (size_t)fc * 16 * 64);
    const bf8_t a1 = *(const bf8_t*)(mr + (size_t)fc * 16 * 64 + 32);
    acc[fc] = __builtin_amdgcn_mfma_f32_16x16x32_bf16(a0, hfr[0], acc[fc], 0, 0, 0);
    acc[fc] = __builtin_amdgcn_mfma_f32_16x16x32_bf16(a1, hfr[1], acc[fc], 0, 0, 0);
  }

  unsigned short* Tb = ((kd0 & 512) ? Tout : Tin) + (size_t)b * N_ * 576;
  const int kdl = kd0 & 511;
  const int j = j0 + r16;
  unsigned short* trow = Tb + (size_t)j * 576 + 64 + kdl + grp * 4;
#pragma unroll
  for (int fc = 0; fc < 4; ++fc) {
    const unsigned lo = (unsigned)f2bf(acc[fc][0]) | ((unsigned)f2bf(acc[fc][1]) << 16);
    const unsigned hi = (unsigned)f2bf(acc[fc][2]) | ((unsigned)f2bf(acc[fc][3]) << 16);
    *(uint2*)(trow + fc * 16) = make_uint2(lo, hi);
  }
}

// ---------- kernel C: gather, 8 lanes/row dwordx4, j-split 2, atomic combine ----------
__global__ __launch_bounds__(256) void gather_msg(
    const unsigned* __restrict__ wsu,
    const unsigned short* __restrict__ Tin,
    const unsigned short* __restrict__ Tout,
    const float* __restrict__ bias,
    float* __restrict__ out) {
  __shared__ unsigned ed[32][260];     // 32 rows x 256 j (stride 260: bank-spread)
  const int blk = blockIdx.x;          // 512
  const int b  = (blk & 7) + 8 * ((blk >> 3) & 1);
  const int rest = blk >> 4;           // 0..31
  const int rb = rest & 15;            // row-block of 32 rows
  const int jh = rest >> 4;            // j-half 0/1
  const int tid = threadIdx.x;
  const int w = tid >> 6, lane = tid & 63;

  // stage 32 rows x 256 edge words (coalesced int4)
  const unsigned* wrow = wsu + ((size_t)(b * N_ + rb * 32)) * N_ + jh * 256;
#pragma unroll
  for (int c = 0; c < 8; ++c) {
    const int idx = c * 256 + tid;     // 0..2047 int4's
    const int row = idx >> 6, col4 = idx & 63;
    *(int4*)&ed[row][col4 * 4] = *(const int4*)(wrow + (size_t)row * N_ + col4 * 4);
  }
  __syncthreads();

  const int row_l = w * 8 + (lane >> 3);     // 0..31
  const int d0 = (lane & 7) * 8;             // 8 d's per lane
  const unsigned* edrow = &ed[row_l][0];
  const char* tinB  = (const char*)Tin  + (size_t)b * N_ * TROWB;
  const char* toutB = (const char*)Tout + (size_t)b * N_ * TROWB;
  unsigned vbase = (unsigned)(jh * 256) * TROWB + (unsigned)d0 * 2;

  float aI[8], aO[8];
#pragma unroll
  for (int q = 0; q < 8; ++q) { aI[q] = 0.f; aO[q] = 0.f; }

#pragma unroll 8
  for (int j = 0; j < 256; ++j) {
    const unsigned wv = edrow[j];
    const uint4 ti = *(const uint4*)(tinB  + (vbase + (wv & 0xFFFFu)));
    const uint4 to = *(const uint4*)(toutB + (vbase + (wv >> 16)));
    aI[0] += __uint_as_float(ti.x << 16);
    aI[1] += __uint_as_float(ti.x & 0xFFFF0000u);
    aI[2] += __uint_as_float(ti.y << 16);
    aI[3] += __uint_as_float(ti.y & 0xFFFF0000u);
    aI[4] += __uint_as_float(ti.z << 16);
    aI[5] += __uint_as_float(ti.z & 0xFFFF0000u);
    aI[6] += __uint_as_float(ti.w << 16);
    aI[7] += __uint_as_float(ti.w & 0xFFFF0000u);
    aO[0] += __uint_as_float(to.x << 16);
    aO[1] += __uint_as_float(to.x & 0xFFFF0000u);
    aO[2] += __uint_as_float(to.y << 16);
    aO[3] += __uint_as_float(to.y & 0xFFFF0000u);
    aO[4] += __uint_as_float(to.z << 16);
    aO[5] += __uint_as_float(to.z & 0xFFFF0000u);
    aO[6] += __uint_as_float(to.w << 16);
    aO[7] += __uint_as_float(to.w & 0xFFFF0000u);
    vbase += TROWB;
  }

  if (jh == 0) {  // fold bias into the jh=0 partial (added exactly once)
#pragma unroll
    for (int q = 0; q < 8; ++q) {
      aI[q] += bias[d0 + q];
      aO[q] += bias[D_ + d0 + q];
    }
  }
  const int row = rb * 32 + row_l;
  float* orow = out + ((size_t)b * N_ + row) * (2 * D_);
#pragma unroll
  for (int q = 0; q < 8; ++q) {
    atomicAdd(orow + d0 + q, aI[q]);
    atomicAdd(orow + D_ + d0 + q, aO[q]);
  }
}

// ---------- fallback (branch-tree kernel) if ws is too small ----------
#define ACCUM(kv, bucket) switch (kv) { \
    case 1: (bucket)[0] += v_; break; case 2: (bucket)[1] += v_; break; \
    case 3: (bucket)[2] += v_; break; case 4: (bucket)[3] += v_; break; \
    case 5: (bucket)[4] += v_; break; case 6: (bucket)[5] += v_; break; \
    case 7: (bucket)[6] += v_; break; case 8: (bucket)[7] += v_; break; \
    default: break; }

__global__ __launch_bounds__(64) void ggnn_fallback(
    const float* __restrict__ h, const int* __restrict__ adj,
    const float* __restrict__ Min, const float* __restrict__ Mout,
    const float* __restrict__ bias, float* __restrict__ out) {
  const int blk = blockIdx.x;
  const int b  = blk / (N_ / 2);
  const int i0 = (blk % (N_ / 2)) * 2;
  const int d  = threadIdx.x;
  float s_in[2][K_], s_out[2][K_];
#pragma unroll
  for (int r = 0; r < 2; ++r)
#pragma unroll
    for (int k = 0; k < K_; ++k) { s_in[r][k] = 0.f; s_out[r][k] = 0.f; }
  const int* rowp0 = adj + (b * N_ + i0) * N_;
  const int* rowp1 = rowp0 + N_;
  const int* colp  = adj + b * N_ * N_ + i0;
  const float* hb  = h + b * N_ * D_ + d;
  for (int j0 = 0; j0 < N_; j0 += 8) {
    float hv[8]; int kr0[8], kr1[8], kc0[8], kc1[8];
#pragma unroll
    for (int m = 0; m < 8; ++m) {
      hv[m] = hb[(j0 + m) * D_];
      kr0[m] = rowp0[j0 + m]; kr1[m] = rowp1[j0 + m];
      kc0[m] = colp[(j0 + m) * N_]; kc1[m] = colp[(j0 + m) * N_ + 1];
    }
#pragma unroll
    for (int m = 0; m < 8; ++m) {
      const float v_ = hv[m];
      ACCUM(kr0[m], s_in[0]); ACCUM(kr1[m], s_in[1]);
      ACCUM(kc0[m], s_out[0]); ACCUM(kc1[m], s_out[1]);
    }
  }
  __shared__ float S[2][2][K_][D_];
#pragma unroll
  for (int r = 0; r < 2; ++r)
#pragma unroll
    for (int k = 0; k < K_; ++k) { S[r][0][k][d] = s_in[r][k]; S[r][1][k][d] = s_out[r][k]; }
  __syncthreads();
  float acc_in[2], acc_out[2];
#pragma unroll
  for (int r = 0; r < 2; ++r) { acc_in[r] = bias[d]; acc_out[r] = bias[D_ + d]; }
  for (int k = 0; k < K_; ++k) {
#pragma unroll
    for (int e0 = 0; e0 < D_; e0 += 4) {
      const float4 mi = *(const float4*)(Min  + (k * D_ + d) * D_ + e0);
      const float4 mo = *(const float4*)(Mout + (k * D_ + d) * D_ + e0);
#pragma unroll
      for (int r = 0; r < 2; ++r) {
        const float4 si = *(const float4*)(&S[r][0][k][e0]);
        const float4 so = *(const float4*)(&S[r][1][k][e0]);
        acc_in[r]  += mi.x * si.x + mi.y * si.y + mi.z * si.z + mi.w * si.w;
        acc_out[r] += mo.x * so.x + mo.y * so.y + mo.z * so.z + mo.w * so.w;
      }
    }
  }
#pragma unroll
  for (int r = 0; r < 2; ++r) {
    out[(b * N_ + i0 + r) * (2 * D_) + d]      = acc_in[r];
    out[(b * N_ + i0 + r) * (2 * D_) + D_ + d] = acc_out[r];
  }
}

extern "C" void kernel_launch(void* const* d_in, const int* in_sizes, int n_in,
                              void* d_out, int out_size, void* d_ws, size_t ws_size,
                              hipStream_t stream) {
  const float* h    = (const float*)d_in[0];
  const int*   adj  = (const int*)d_in[1];
  const float* Min  = (const float*)d_in[3];
  const float* Mout = (const float*)d_in[4];
  const float* bias = (const float*)d_in[5];
  float* out = (float*)d_out;

  if (ws_size < WSU_BYTES + 2 * T_BYTES + HBF_BYTES + MBF_BYTES) {
    hipLaunchKernelGGL(ggnn_fallback, dim3(B_ * N_ / 2), dim3(64), 0, stream,
                       h, adj, Min, Mout, bias, out);
    return;
  }
  unsigned*       wsu  = (unsigned*)d_ws;
  unsigned short* Tin  = (unsigned short*)((char*)d_ws + WSU_BYTES);
  unsigned short* Tout = (unsigned short*)((char*)d_ws + WSU_BYTES + T_BYTES);
  unsigned short* hbf  = (unsigned short*)((char*)d_ws + WSU_BYTES + 2 * T_BYTES);
  unsigned short* Mbf  = (unsigned short*)((char*)d_ws + WSU_BYTES + 2 * T_BYTES + HBF_BYTES);

  hipLaunchKernelGGL(conv_inputs,  dim3(512),  dim3(256), 0, stream,
                     h, Min, Mout, hbf, Mbf, Tin, Tout, out);
  hipLaunchKernelGGL(prep_adj,     dim3(1024), dim3(256), 0, stream, adj, wsu);
  hipLaunchKernelGGL(build_T_mfma, dim3(2048), dim3(256), 0, stream, hbf, Mbf, Tin, Tout);
  hipLaunchKernelGGL(gather_msg,   dim3(512),  dim3(256), 0, stream,
                     wsu, Tin, Tout, bias, out);
}

// Round 7
// 166.208 us; speedup vs baseline: 1.4095x; 1.4095x over previous
//
#include <hip/hip_runtime.h>
#include <hip/hip_fp16.h>

#define B_ 16
#define N_ 512
#define D_ 64
#define K_ 8

// ---------------- ws layout ----------------
// wsu : [B][N][N] uint {kin*128 | (kout*128)<<16}   16,777,216 B
// Tin : [B][N][9][64] f16                            9,437,184 B
// Tout: [B][N][9][64] f16   (MUST follow Tin)        9,437,184 B
// hbf : [B][N][64] bf16                              1,048,576 B
// Mbf : [2][8][64][64] bf16                            131,072 B
#define WSU_BYTES ((size_t)B_ * N_ * N_ * 4)
#define T_BYTES   ((size_t)B_ * N_ * (K_ + 1) * D_ * 2)
#define HBF_BYTES ((size_t)B_ * N_ * D_ * 2)
#define MBF_BYTES ((size_t)2 * K_ * D_ * D_ * 2)
#define TROWB 1152  // (K+1)*D*2 bytes per j row

typedef __attribute__((ext_vector_type(8))) short bf8_t;   // 8 bf16
typedef __attribute__((ext_vector_type(4))) float f4_t;    // 4 f32 acc

__device__ __forceinline__ unsigned short f2bf(float x) {  // RNE f32->bf16
  union { float f; unsigned u; } c; c.f = x;
  unsigned r = c.u + 0x7FFFu + ((c.u >> 16) & 1u);
  return (unsigned short)(r >> 16);
}

// ---------- kernel 0: bf16 conversions + zero T slot 0 ----------
__global__ __launch_bounds__(256) void conv_inputs(
    const float* __restrict__ h, const float* __restrict__ Min,
    const float* __restrict__ Mout,
    unsigned short* __restrict__ hbf, unsigned short* __restrict__ Mbf,
    unsigned short* __restrict__ Tin, unsigned short* __restrict__ Tout) {
  const int g = blockIdx.x * 256 + threadIdx.x;   // 131072 threads
  {  // h: 131072 float4 groups
    const float4 v = ((const float4*)h)[g];
    ushort4 o; o.x = f2bf(v.x); o.y = f2bf(v.y); o.z = f2bf(v.z); o.w = f2bf(v.w);
    ((ushort4*)hbf)[g] = o;
  }
  if (g < 8192) {          // Min
    const float4 v = ((const float4*)Min)[g];
    ushort4 o; o.x = f2bf(v.x); o.y = f2bf(v.y); o.z = f2bf(v.z); o.w = f2bf(v.w);
    ((ushort4*)Mbf)[g] = o;
  } else if (g < 16384) {  // Mout
    const int t = g - 8192;
    const float4 v = ((const float4*)Mout)[t];
    ushort4 o; o.x = f2bf(v.x); o.y = f2bf(v.y); o.z = f2bf(v.z); o.w = f2bf(v.w);
    ((ushort4*)Mbf)[8192 + t] = o;
  }
  {  // zero slot k=0 of T: 8192 rows x 16 ushort4 chunks (f16 zero == 0x0000)
    const int row = g >> 4, part = g & 15;
    const ushort4 z = make_ushort4(0, 0, 0, 0);
    ((ushort4*)(Tin  + (size_t)row * 576))[part] = z;
    ((ushort4*)(Tout + (size_t)row * 576))[part] = z;
  }
}

// ---------- kernel A: transpose + pack PRE-SHIFTED edge byte-offsets ----------
__global__ __launch_bounds__(256) void prep_adj(const int* __restrict__ adj,
                                                unsigned* __restrict__ wsu) {
  __shared__ int ta[64][65];
  __shared__ int tb[64][65];
  const int blk = blockIdx.x;          // 1024
  const int xcd = blk & 7, rest = blk >> 3;
  const int b = xcd + 8 * (rest & 1);  // batch b -> XCD b%8
  const int tile = rest >> 1;          // 0..63
  const int i0 = (tile >> 3) * 64, j0 = (tile & 7) * 64;
  const int lane = threadIdx.x & 63, w = threadIdx.x >> 6;
  const int* ab = adj + (size_t)b * N_ * N_;
#pragma unroll
  for (int r = w; r < 64; r += 4) {
    ta[r][lane] = ab[(size_t)(i0 + r) * N_ + j0 + lane];
    tb[r][lane] = ab[(size_t)(j0 + r) * N_ + i0 + lane];
  }
  __syncthreads();
  unsigned* wb = wsu + (size_t)b * N_ * N_;
#pragma unroll
  for (int r = w; r < 64; r += 4) {
    wb[(size_t)(i0 + r) * N_ + j0 + lane] =
        (unsigned)(ta[r][lane] << 7) | ((unsigned)tb[lane][r] << 23);
  }
}

// ---------- kernel B: T = M' x h^T via MFMA (bf16 in, f16 out) ----------
__global__ __launch_bounds__(256) void build_T_mfma(
    const unsigned short* __restrict__ hbf,   // [B][N][64] bf16
    const unsigned short* __restrict__ Mbf,   // [1024][64] bf16
    unsigned short* __restrict__ Tin,
    unsigned short* __restrict__ Tout) {
  const int blk = blockIdx.x;               // 2048
  const int b   = (blk & 7) + 8 * ((blk >> 3) & 1);
  const int u   = blk >> 4;                 // 0..127
  const int kdt = u >> 3;                   // 0..15 : kd-tile of 64
  const int jt4 = u & 7;                    // 0..7  : 4 j-tiles of 16
  const int w = threadIdx.x >> 6, l = threadIdx.x & 63;
  const int j0  = (jt4 * 4 + w) * 16;
  const int kd0 = kdt * 64;
  const int r16 = l & 15, grp = l >> 4;

  const unsigned short* hr = hbf + ((size_t)(b * N_ + j0 + r16)) * 64 + grp * 8;
  bf8_t hfr[2];
  hfr[0] = *(const bf8_t*)(hr);
  hfr[1] = *(const bf8_t*)(hr + 32);

  const unsigned short* mr = Mbf + (size_t)(kd0 + r16) * 64 + grp * 8;

  f4_t acc[4];
#pragma unroll
  for (int fc = 0; fc < 4; ++fc) acc[fc] = (f4_t)(0.f);
#pragma unroll
  for (int fc = 0; fc < 4; ++fc) {
    const bf8_t a0 = *(const bf8_t*)(mr + (size_t)fc * 16 * 64);
    const bf8_t a1 = *(const bf8_t*)(mr + (size_t)fc * 16 * 64 + 32);
    acc[fc] = __builtin_amdgcn_mfma_f32_16x16x32_bf16(a0, hfr[0], acc[fc], 0, 0, 0);
    acc[fc] = __builtin_amdgcn_mfma_f32_16x16x32_bf16(a1, hfr[1], acc[fc], 0, 0, 0);
  }

  unsigned short* Tb = ((kd0 & 512) ? Tout : Tin) + (size_t)b * N_ * 576;
  const int kdl = kd0 & 511;
  const int j = j0 + r16;
  unsigned short* trow = Tb + (size_t)j * 576 + 64 + kdl + grp * 4;
#pragma unroll
  for (int fc = 0; fc < 4; ++fc) {
    const __half2 lo = __floats2half2_rn(acc[fc][0], acc[fc][1]);
    const __half2 hi = __floats2half2_rn(acc[fc][2], acc[fc][3]);
    uint2 pk;
    pk.x = *(const unsigned*)&lo;
    pk.y = *(const unsigned*)&hi;
    *(uint2*)(trow + fc * 16) = pk;
  }
}

// ---------- kernel C: gather, f16 packed adds, 16 rows/block, no atomics ----------
__global__ __launch_bounds__(512) void gather_msg(
    const unsigned* __restrict__ wsu,
    const unsigned short* __restrict__ Tin,   // Tout = Tin + T_BYTES (contiguous)
    const float* __restrict__ bias,
    float* __restrict__ out) {
  __shared__ unsigned ed[16][512];   // 32 KB edge words for 16 rows
  const int blk = blockIdx.x;        // 512
  const int b  = (blk & 7) + 8 * ((blk >> 3) & 1);
  const int rb = blk >> 4;           // 0..31 : row-block of 16
  const int tid = threadIdx.x;
  const int w = tid >> 6, lane = tid & 63;
  const int half = lane >> 5, lane5 = lane & 31;
  const int dir = lane5 >> 4;        // 0 = in, 1 = out
  const int dl  = lane5 & 15;        // d-quad index (4 d's per lane)
  const int row_l = w * 2 + half;

  // stage 16 rows x 512 edge words (rows contiguous in wsu)
  {
    const int4* src = (const int4*)(wsu + ((size_t)(b * N_ + rb * 16)) * N_);
    int4* dst = (int4*)ed;
#pragma unroll
    for (int c = 0; c < 4; ++c) dst[c * 512 + tid] = src[c * 512 + tid];
  }
  __syncthreads();

  const unsigned shr_ = (unsigned)dir * 16u;
  const char* base = (const char*)Tin + (size_t)b * N_ * TROWB;
  unsigned vb = (unsigned)dir * (unsigned)T_BYTES + (unsigned)dl * 8u;
  const unsigned* edrow = &ed[row_l][0];

  float fa0 = 0.f, fa1 = 0.f, fa2 = 0.f, fa3 = 0.f;
  for (int jw = 0; jw < 8; ++jw) {           // 8 windows x 64 j
    __half2 a0 = __floats2half2_rn(0.f, 0.f);
    __half2 a1 = __floats2half2_rn(0.f, 0.f);
#pragma unroll 4
    for (int j4 = 0; j4 < 16; ++j4) {
      const uint4 ew = *(const uint4*)(edrow + jw * 64 + j4 * 4);
#pragma unroll
      for (int t = 0; t < 4; ++t) {
        const unsigned wvv = (t == 0) ? ew.x : (t == 1) ? ew.y : (t == 2) ? ew.z : ew.w;
        const unsigned off = (wvv >> shr_) & 0xFFFFu;
        const uint2 u = *(const uint2*)(base + (vb + off));
        a0 = __hadd2(a0, *(const __half2*)&u.x);
        a1 = __hadd2(a1, *(const __half2*)&u.y);
        vb += TROWB;
      }
    }
    const float2 f0 = __half22float2(a0);
    const float2 f1 = __half22float2(a1);
    fa0 += f0.x; fa1 += f0.y; fa2 += f1.x; fa3 += f1.y;
  }

  const int row = rb * 16 + row_l;
  const int d0 = dl * 4;
  float4 r;
  r.x = fa0 + bias[dir * 64 + d0];
  r.y = fa1 + bias[dir * 64 + d0 + 1];
  r.z = fa2 + bias[dir * 64 + d0 + 2];
  r.w = fa3 + bias[dir * 64 + d0 + 3];
  *(float4*)(out + ((size_t)b * N_ + row) * (2 * D_) + dir * 64 + d0) = r;
}

// ---------- fallback (branch-tree kernel) if ws is too small ----------
#define ACCUM(kv, bucket) switch (kv) { \
    case 1: (bucket)[0] += v_; break; case 2: (bucket)[1] += v_; break; \
    case 3: (bucket)[2] += v_; break; case 4: (bucket)[3] += v_; break; \
    case 5: (bucket)[4] += v_; break; case 6: (bucket)[5] += v_; break; \
    case 7: (bucket)[6] += v_; break; case 8: (bucket)[7] += v_; break; \
    default: break; }

__global__ __launch_bounds__(64) void ggnn_fallback(
    const float* __restrict__ h, const int* __restrict__ adj,
    const float* __restrict__ Min, const float* __restrict__ Mout,
    const float* __restrict__ bias, float* __restrict__ out) {
  const int blk = blockIdx.x;
  const int b  = blk / (N_ / 2);
  const int i0 = (blk % (N_ / 2)) * 2;
  const int d  = threadIdx.x;
  float s_in[2][K_], s_out[2][K_];
#pragma unroll
  for (int r = 0; r < 2; ++r)
#pragma unroll
    for (int k = 0; k < K_; ++k) { s_in[r][k] = 0.f; s_out[r][k] = 0.f; }
  const int* rowp0 = adj + (b * N_ + i0) * N_;
  const int* rowp1 = rowp0 + N_;
  const int* colp  = adj + b * N_ * N_ + i0;
  const float* hb  = h + b * N_ * D_ + d;
  for (int j0 = 0; j0 < N_; j0 += 8) {
    float hv[8]; int kr0[8], kr1[8], kc0[8], kc1[8];
#pragma unroll
    for (int m = 0; m < 8; ++m) {
      hv[m] = hb[(j0 + m) * D_];
      kr0[m] = rowp0[j0 + m]; kr1[m] = rowp1[j0 + m];
      kc0[m] = colp[(j0 + m) * N_]; kc1[m] = colp[(j0 + m) * N_ + 1];
    }
#pragma unroll
    for (int m = 0; m < 8; ++m) {
      const float v_ = hv[m];
      ACCUM(kr0[m], s_in[0]); ACCUM(kr1[m], s_in[1]);
      ACCUM(kc0[m], s_out[0]); ACCUM(kc1[m], s_out[1]);
    }
  }
  __shared__ float S[2][2][K_][D_];
#pragma unroll
  for (int r = 0; r < 2; ++r)
#pragma unroll
    for (int k = 0; k < K_; ++k) { S[r][0][k][d] = s_in[r][k]; S[r][1][k][d] = s_out[r][k]; }
  __syncthreads();
  float acc_in[2], acc_out[2];
#pragma unroll
  for (int r = 0; r < 2; ++r) { acc_in[r] = bias[d]; acc_out[r] = bias[D_ + d]; }
  for (int k = 0; k < K_; ++k) {
#pragma unroll
    for (int e0 = 0; e0 < D_; e0 += 4) {
      const float4 mi = *(const float4*)(Min  + (k * D_ + d) * D_ + e0);
      const float4 mo = *(const float4*)(Mout + (k * D_ + d) * D_ + e0);
#pragma unroll
      for (int r = 0; r < 2; ++r) {
        const float4 si = *(const float4*)(&S[r][0][k][e0]);
        const float4 so = *(const float4*)(&S[r][1][k][e0]);
        acc_in[r]  += mi.x * si.x + mi.y * si.y + mi.z * si.z + mi.w * si.w;
        acc_out[r] += mo.x * so.x + mo.y * so.y + mo.z * so.z + mo.w * so.w;
      }
    }
  }
#pragma unroll
  for (int r = 0; r < 2; ++r) {
    out[(b * N_ + i0 + r) * (2 * D_) + d]      = acc_in[r];
    out[(b * N_ + i0 + r) * (2 * D_) + D_ + d] = acc_out[r];
  }
}

extern "C" void kernel_launch(void* const* d_in, const int* in_sizes, int n_in,
                              void* d_out, int out_size, void* d_ws, size_t ws_size,
                              hipStream_t stream) {
  const float* h    = (const float*)d_in[0];
  const int*   adj  = (const int*)d_in[1];
  const float* Min  = (const float*)d_in[3];
  const float* Mout = (const float*)d_in[4];
  const float* bias = (const float*)d_in[5];
  float* out = (float*)d_out;

  if (ws_size < WSU_BYTES + 2 * T_BYTES + HBF_BYTES + MBF_BYTES) {
    hipLaunchKernelGGL(ggnn_fallback, dim3(B_ * N_ / 2), dim3(64), 0, stream,
                       h, adj, Min, Mout, bias, out);
    return;
  }
  unsigned*       wsu  = (unsigned*)d_ws;
  unsigned short* Tin  = (unsigned short*)((char*)d_ws + WSU_BYTES);
  unsigned short* Tout = (unsigned short*)((char*)d_ws + WSU_BYTES + T_BYTES);
  unsigned short* hbf  = (unsigned short*)((char*)d_ws + WSU_BYTES + 2 * T_BYTES);
  unsigned short* Mbf  = (unsigned short*)((char*)d_ws + WSU_BYTES + 2 * T_BYTES + HBF_BYTES);

  hipLaunchKernelGGL(conv_inputs,  dim3(512),  dim3(256), 0, stream,
                     h, Min, Mout, hbf, Mbf, Tin, Tout);
  hipLaunchKernelGGL(prep_adj,     dim3(1024), dim3(256), 0, stream, adj, wsu);
  hipLaunchKernelGGL(build_T_mfma, dim3(2048), dim3(256), 0, stream, hbf, Mbf, Tin, Tout);
  hipLaunchKernelGGL(gather_msg,   dim3(512),  dim3(512), 0, stream,
                     wsu, Tin, bias, out);
}